// Round 1
// baseline (260.918 us; speedup 1.0000x reference)
//
#include <hip/hip_runtime.h>
#include <math.h>

namespace {
constexpr int NZ = 48, NY = 256, NX = 512;
constexpr int SY = NX;           // y stride (elements)
constexpr int SZ = NX * NY;      // z stride (elements)
constexpr int NTOT = NZ * NY * NX;
}

// first gradient, torch.gradient semantics: central interior, one-sided edges
__device__ __forceinline__ float grad1(const float* __restrict__ f, int base,
                                       int i, int n, int stride, float inv_h) {
    if (i == 0)     return (f[base + stride] - f[base]) * inv_h;
    if (i == n - 1) return (f[base] - f[base - stride]) * inv_h;
    return (f[base + stride] - f[base - stride]) * (0.5f * inv_h);
}

// g = grad(f) at i; gg = grad(grad(f)) at i  (exact grad-of-grad semantics)
__device__ __forceinline__ void grad2(const float* __restrict__ f, int base,
                                      int i, int n, int stride, float inv_h,
                                      float& g, float& gg) {
    const float h1 = inv_h;
    const float h2 = 0.5f * inv_h;
    const float c = f[base];
    if (i >= 2 && i <= n - 3) {
        const float m2 = f[base - 2 * stride];
        const float m1 = f[base - stride];
        const float p1 = f[base + stride];
        const float p2 = f[base + 2 * stride];
        g = (p1 - m1) * h2;
        gg = ((p2 - c) * h2 - (c - m2) * h2) * h2;   // (g(i+1)-g(i-1))/(2h)
    } else if (i == 0) {
        const float p1 = f[base + stride];
        const float p2 = f[base + 2 * stride];
        g = (p1 - c) * h1;                            // one-sided
        gg = ((p2 - c) * h2 - g) * h1;                // (g(1)-g(0))/h
    } else if (i == 1) {
        const float m1 = f[base - stride];
        const float p1 = f[base + stride];
        const float p2 = f[base + 2 * stride];
        g = (p1 - m1) * h2;
        gg = ((p2 - c) * h2 - (c - m1) * h1) * h2;    // (g(2)-g(0))/(2h)
    } else if (i == n - 2) {
        const float m2 = f[base - 2 * stride];
        const float m1 = f[base - stride];
        const float p1 = f[base + stride];
        g = (p1 - m1) * h2;
        gg = ((p1 - c) * h1 - (c - m2) * h2) * h2;    // (g(n-1)-g(n-3))/(2h)
    } else { // i == n - 1
        const float m2 = f[base - 2 * stride];
        const float m1 = f[base - stride];
        g = (c - m1) * h1;                            // one-sided
        gg = (g - (c - m2) * h2) * h1;                // (g(n-1)-g(n-2))/h
    }
}

__global__ __launch_bounds__(256)
void pe_tendencies_kernel(const float* __restrict__ u, const float* __restrict__ v,
                          const float* __restrict__ w, const float* __restrict__ T,
                          const float* __restrict__ q, const float* __restrict__ p,
                          const float* __restrict__ rho,
                          const float* __restrict__ F_u, const float* __restrict__ F_v,
                          const float* __restrict__ F_w, const float* __restrict__ Q,
                          const float* __restrict__ S,
                          const float* __restrict__ nu_p, const float* __restrict__ kappa_p,
                          float* __restrict__ out) {
    const int idx = blockIdx.x * blockDim.x + threadIdx.x;
    if (idx >= NTOT) return;
    const int x = idx & (NX - 1);
    const int y = (idx >> 9) & (NY - 1);
    const int z = idx >> 17;

    const float inv_dx = 1.0f / 100000.0f;
    const float inv_dy = 1.0f / 100000.0f;
    const float inv_dz = 1.0f / 500.0f;

    const float nu = nu_p[0];
    const float kappa = kappa_p[0];

    // --- u, v, w, T: first + second gradients on all three axes ---
    float du_dx, du_dy, du_dz, lux, luy, luz;
    grad2(u, idx, x, NX, 1, inv_dx, du_dx, lux);
    grad2(u, idx, y, NY, SY, inv_dy, du_dy, luy);
    grad2(u, idx, z, NZ, SZ, inv_dz, du_dz, luz);

    float dv_dx, dv_dy, dv_dz, lvx, lvy, lvz;
    grad2(v, idx, x, NX, 1, inv_dx, dv_dx, lvx);
    grad2(v, idx, y, NY, SY, inv_dy, dv_dy, lvy);
    grad2(v, idx, z, NZ, SZ, inv_dz, dv_dz, lvz);

    float dw_dx, dw_dy, dw_dz, lwx, lwy, lwz;
    grad2(w, idx, x, NX, 1, inv_dx, dw_dx, lwx);
    grad2(w, idx, y, NY, SY, inv_dy, dw_dy, lwy);
    grad2(w, idx, z, NZ, SZ, inv_dz, dw_dz, lwz);

    float dT_dx, dT_dy, dT_dz, lTx, lTy, lTz;
    grad2(T, idx, x, NX, 1, inv_dx, dT_dx, lTx);
    grad2(T, idx, y, NY, SY, inv_dy, dT_dy, lTy);
    grad2(T, idx, z, NZ, SZ, inv_dz, dT_dz, lTz);

    // --- p, rho, q: first gradients only ---
    const float dp_dx = grad1(p, idx, x, NX, 1, inv_dx);
    const float dp_dy = grad1(p, idx, y, NY, SY, inv_dy);
    const float dp_dz = grad1(p, idx, z, NZ, SZ, inv_dz);

    const float drho_dx = grad1(rho, idx, x, NX, 1, inv_dx);
    const float drho_dy = grad1(rho, idx, y, NY, SY, inv_dy);
    const float drho_dz = grad1(rho, idx, z, NZ, SZ, inv_dz);

    const float dq_dx = grad1(q, idx, x, NX, 1, inv_dx);
    const float dq_dy = grad1(q, idx, y, NY, SY, inv_dy);
    const float dq_dz = grad1(q, idx, z, NZ, SZ, inv_dz);

    // --- centers & forcings ---
    const float uc = u[idx], vc = v[idx], wc = w[idx];
    const float Tc = T[idx], pc = p[idx], rhoc = rho[idx];
    const float fu = F_u[idx], fv = F_v[idx], fw = F_w[idx];
    const float Qc = Q[idx], Sc = S[idx];

    // Coriolis: lat = linspace(-pi/2, pi/2, NY); f = 2*OMEGA*sin(lat)
    const double lat = -M_PI * 0.5 + (M_PI / (double)(NY - 1)) * (double)y;
    const float fcor = 2.0f * 7.2921e-5f * (float)sin(lat);

    const float rho_safe = rhoc + 1e-10f;

    const float u_adv = uc * du_dx + vc * du_dy + wc * du_dz;
    const float v_adv = uc * dv_dx + vc * dv_dy + wc * dv_dz;
    const float w_adv = uc * dw_dx + vc * dw_dy + wc * dw_dz;

    const float visc_u = nu * (lux + luy + luz);
    const float visc_v = nu * (lvx + lvy + lvz);
    const float visc_w = nu * (lwx + lwy + lwz);

    const float du_dt = -u_adv - dp_dx / rho_safe + fcor * vc + visc_u + fu;
    const float dv_dt = -v_adv - dp_dy / rho_safe - fcor * uc + visc_v + fv;
    const float dw_dt = -w_adv - dp_dz / rho_safe - 9.80665f + visc_w + fw;

    const float T_adv = uc * dT_dx + vc * dT_dy + wc * dT_dz;
    const float diff_T = kappa * (lTx + lTy + lTz);
    const float kappa_ratio = 287.0f / 1004.0f;
    const float adiabatic = kappa_ratio * Tc * wc * dp_dz / (pc + 1e-10f);
    const float dT_dt = -T_adv + diff_T + adiabatic + Qc / 1004.0f;

    const float q_adv = uc * dq_dx + vc * dq_dy + wc * dq_dz;
    const float dq_dt = -q_adv + Sc;

    const float div = du_dx + dv_dy + dw_dz;
    const float drho_dt = -rhoc * div - uc * drho_dx - vc * drho_dy - wc * drho_dz;
    const float dp_dt = 287.0f * (rhoc * dT_dt + Tc * drho_dt);

    out[0 * NTOT + idx] = du_dt;
    out[1 * NTOT + idx] = dv_dt;
    out[2 * NTOT + idx] = dw_dt;
    out[3 * NTOT + idx] = dT_dt;
    out[4 * NTOT + idx] = dq_dt;
    out[5 * NTOT + idx] = dp_dt;
    out[6 * NTOT + idx] = drho_dt;
}

extern "C" void kernel_launch(void* const* d_in, const int* in_sizes, int n_in,
                              void* d_out, int out_size, void* d_ws, size_t ws_size,
                              hipStream_t stream) {
    const float* u     = (const float*)d_in[0];
    const float* v     = (const float*)d_in[1];
    const float* w     = (const float*)d_in[2];
    const float* T     = (const float*)d_in[3];
    const float* q     = (const float*)d_in[4];
    const float* p     = (const float*)d_in[5];
    const float* rho   = (const float*)d_in[6];
    const float* F_u   = (const float*)d_in[7];
    const float* F_v   = (const float*)d_in[8];
    const float* F_w   = (const float*)d_in[9];
    const float* Q     = (const float*)d_in[10];
    const float* S     = (const float*)d_in[11];
    const float* nu    = (const float*)d_in[12];
    const float* kappa = (const float*)d_in[13];
    float* out = (float*)d_out;

    const int block = 256;
    const int grid = (NTOT + block - 1) / block;  // 24576
    pe_tendencies_kernel<<<grid, block, 0, stream>>>(u, v, w, T, q, p, rho,
                                                     F_u, F_v, F_w, Q, S,
                                                     nu, kappa, out);
}

// Round 2
// 188.330 us; speedup vs baseline: 1.3854x; 1.3854x over previous
//
#include <hip/hip_runtime.h>
#include <math.h>

typedef float f4 __attribute__((ext_vector_type(4)));

namespace {
constexpr int NZ = 48, NY = 256, NX = 512;
constexpr int SY = NX;           // y stride (elements)
constexpr int SZ = NX * NY;      // z stride (elements)
constexpr int NTOT = NZ * NY * NX;
constexpr float INV_DX = 1.0f / 100000.0f;
constexpr float INV_DY = 1.0f / 100000.0f;
constexpr float INV_DZ = 1.0f / 500.0f;
}

__device__ __forceinline__ f4 sp(float s) { return (f4){s, s, s, s}; }

__device__ __forceinline__ f4 ldv(const float* __restrict__ f, int e) {
    return *reinterpret_cast<const f4*>(f + e);
}

// ---- x-axis: per-element window [L | C | R], thread covers i = x0..x0+3 ----
// interior: g=(p1-m1)/2h ; gg = ((p2-c)/2h - (c-m2)/2h)/2h  (grad-of-grad)
__device__ __forceinline__ void grad2x(f4 L, f4 C, f4 R, int x0, float inv_h,
                                       f4& g, f4& gg) {
    const float h1 = inv_h, h2 = 0.5f * inv_h;
    float win[12] = {L[0], L[1], L[2], L[3], C[0], C[1], C[2], C[3],
                     R[0], R[1], R[2], R[3]};
#pragma unroll
    for (int j = 0; j < 4; ++j) {
        g[j]  = (win[5 + j] - win[3 + j]) * h2;
        gg[j] = ((win[6 + j] - win[4 + j]) * h2 - (win[4 + j] - win[2 + j]) * h2) * h2;
    }
    if (x0 == 0) {                       // i==0 and i==1 edge formulas
        g[0]  = (C[1] - C[0]) * h1;
        gg[0] = ((C[2] - C[0]) * h2 - g[0]) * h1;
        gg[1] = ((C[3] - C[1]) * h2 - (C[1] - C[0]) * h1) * h2;
    } else if (x0 == NX - 4) {           // i==n-2 and i==n-1
        gg[2] = ((C[3] - C[2]) * h1 - (C[2] - C[0]) * h2) * h2;
        g[3]  = (C[3] - C[2]) * h1;
        gg[3] = (g[3] - (C[3] - C[1]) * h2) * h1;
    }
}

__device__ __forceinline__ f4 grad1x(f4 L, f4 C, f4 R, int x0, float inv_h) {
    const float h1 = inv_h, h2 = 0.5f * inv_h;
    f4 g;
    g[0] = (C[1] - L[3]) * h2;
    g[1] = (C[2] - C[0]) * h2;
    g[2] = (C[3] - C[1]) * h2;
    g[3] = (R[0] - C[2]) * h2;
    if (x0 == 0)            g[0] = (C[1] - C[0]) * h1;
    else if (x0 == NX - 4)  g[3] = (C[3] - C[2]) * h1;
    return g;
}

// ---- y/z axes: whole-vector stencil, index i uniform across the f4 ----
__device__ __forceinline__ void grad2v(f4 m2, f4 m1, f4 c, f4 p1, f4 p2,
                                       int i, int n, float inv_h, f4& g, f4& gg) {
    const float h1 = inv_h, h2 = 0.5f * inv_h;
    if (i >= 2 && i <= n - 3) {
        g  = (p1 - m1) * sp(h2);
        gg = ((p2 - c) * sp(h2) - (c - m2) * sp(h2)) * sp(h2);
    } else if (i == 0) {
        g  = (p1 - c) * sp(h1);
        gg = ((p2 - c) * sp(h2) - g) * sp(h1);
    } else if (i == 1) {
        g  = (p1 - m1) * sp(h2);
        gg = ((p2 - c) * sp(h2) - (c - m1) * sp(h1)) * sp(h2);
    } else if (i == n - 2) {
        g  = (p1 - m1) * sp(h2);
        gg = ((p1 - c) * sp(h1) - (c - m2) * sp(h2)) * sp(h2);
    } else { // i == n-1
        g  = (c - m1) * sp(h1);
        gg = (g - (c - m2) * sp(h2)) * sp(h1);
    }
}

__device__ __forceinline__ f4 grad1v(f4 m1, f4 c, f4 p1, int i, int n, float inv_h) {
    if (i == 0)     return (p1 - c) * sp(inv_h);
    if (i == n - 1) return (c - m1) * sp(inv_h);
    return (p1 - m1) * sp(0.5f * inv_h);
}

struct Offs {
    int xm, xp;                  // element offsets to left/right f4 (clamped)
    int m1y, m2y, p1y, p2y;      // clamped y offsets
    int m1z, m2z, p1z, p2z;      // clamped z offsets
    int x0, y, z;
};

__device__ __forceinline__ void field_grad2(const float* __restrict__ f, int e,
                                            const Offs& o, f4 C,
                                            f4& gx, f4& gy, f4& gz, f4& lap) {
    f4 L = ldv(f, e + o.xm);
    f4 R = ldv(f, e + o.xp);
    f4 gg;
    grad2x(L, C, R, o.x0, INV_DX, gx, gg);
    lap = gg;
    grad2v(ldv(f, e + o.m2y), ldv(f, e + o.m1y), C, ldv(f, e + o.p1y),
           ldv(f, e + o.p2y), o.y, NY, INV_DY, gy, gg);
    lap += gg;
    grad2v(ldv(f, e + o.m2z), ldv(f, e + o.m1z), C, ldv(f, e + o.p1z),
           ldv(f, e + o.p2z), o.z, NZ, INV_DZ, gz, gg);
    lap += gg;
}

__device__ __forceinline__ void field_grad1(const float* __restrict__ f, int e,
                                            const Offs& o, f4 C,
                                            f4& gx, f4& gy, f4& gz) {
    f4 L = ldv(f, e + o.xm);
    f4 R = ldv(f, e + o.xp);
    gx = grad1x(L, C, R, o.x0, INV_DX);
    gy = grad1v(ldv(f, e + o.m1y), C, ldv(f, e + o.p1y), o.y, NY, INV_DY);
    gz = grad1v(ldv(f, e + o.m1z), C, ldv(f, e + o.p1z), o.z, NZ, INV_DZ);
}

__global__ __launch_bounds__(256)
void pe_tendencies_v2(const float* __restrict__ u, const float* __restrict__ v,
                      const float* __restrict__ w, const float* __restrict__ T,
                      const float* __restrict__ q, const float* __restrict__ p,
                      const float* __restrict__ rho,
                      const float* __restrict__ F_u, const float* __restrict__ F_v,
                      const float* __restrict__ F_w, const float* __restrict__ Q,
                      const float* __restrict__ S,
                      const float* __restrict__ nu_p, const float* __restrict__ kappa_p,
                      float* __restrict__ out) {
    const int tid = blockIdx.x * 256 + threadIdx.x;   // one thread = 4 x-points
    const int e = tid << 2;                           // element base index
    const int x0 = (tid & 127) << 2;
    const int y = (tid >> 7) & 255;
    const int z = tid >> 15;

    Offs o;
    o.x0 = x0; o.y = y; o.z = z;
    o.xm = (x0 > 0) ? -4 : 0;
    o.xp = (x0 < NX - 4) ? 4 : 0;
    o.m1y = (y > 0) ? -SY : 0;
    o.m2y = (y > 1) ? -2 * SY : o.m1y;
    o.p1y = (y < NY - 1) ? SY : 0;
    o.p2y = (y < NY - 2) ? 2 * SY : o.p1y;
    o.m1z = (z > 0) ? -SZ : 0;
    o.m2z = (z > 1) ? -2 * SZ : o.m1z;
    o.p1z = (z < NZ - 1) ? SZ : 0;
    o.p2z = (z < NZ - 2) ? 2 * SZ : o.p1z;

    const float nu = nu_p[0];
    const float kap = kappa_p[0];

    const f4 uc = ldv(u, e);
    const f4 vc = ldv(v, e);
    const f4 wc = ldv(w, e);

    f4 gx, gy, gz, lap;

    // u
    field_grad2(u, e, o, uc, gx, gy, gz, lap);
    f4 du_dx = gx;
    f4 acc_u = sp(nu) * lap - (uc * gx + vc * gy + wc * gz);
    // v
    field_grad2(v, e, o, vc, gx, gy, gz, lap);
    f4 dv_dy = gy;
    f4 acc_v = sp(nu) * lap - (uc * gx + vc * gy + wc * gz);
    // w
    field_grad2(w, e, o, wc, gx, gy, gz, lap);
    f4 dw_dz = gz;
    f4 acc_w = sp(nu) * lap - (uc * gx + vc * gy + wc * gz);

    f4 div = du_dx + dv_dy + dw_dz;

    // T
    const f4 Tc = ldv(T, e);
    field_grad2(T, e, o, Tc, gx, gy, gz, lap);
    f4 acc_T = sp(kap) * lap - (uc * gx + vc * gy + wc * gz);

    // rho (grad1)
    const f4 rhoc = ldv(rho, e);
    field_grad1(rho, e, o, rhoc, gx, gy, gz);
    f4 acc_rho = -rhoc * div - uc * gx - vc * gy - wc * gz;

    // p (grad1)
    const f4 pc = ldv(p, e);
    field_grad1(p, e, o, pc, gx, gy, gz);
    const f4 inv_rs = sp(1.0f) / (rhoc + sp(1e-10f));
    acc_u -= gx * inv_rs;
    acc_v -= gy * inv_rs;
    acc_w -= gz * inv_rs;
    acc_T += sp(287.0f / 1004.0f) * Tc * wc * gz / (pc + sp(1e-10f));

    // q (grad1)
    const f4 qc = ldv(q, e);
    field_grad1(q, e, o, qc, gx, gy, gz);
    f4 acc_q = -(uc * gx + vc * gy + wc * gz);

    // Coriolis
    const double lat = -M_PI * 0.5 + (M_PI / 255.0) * (double)y;
    const float fc = 2.0f * 7.2921e-5f * (float)sin(lat);
    acc_u += sp(fc) * vc;
    acc_v -= sp(fc) * uc;

    // forcings / sources
    acc_u += ldv(F_u, e);
    acc_v += ldv(F_v, e);
    acc_w += ldv(F_w, e) - sp(9.80665f);
    acc_T += ldv(Q, e) * sp(1.0f / 1004.0f);
    acc_q += ldv(S, e);

    const f4 acc_p = sp(287.0f) * (rhoc * acc_T + Tc * acc_rho);

    *reinterpret_cast<f4*>(out + 0 * NTOT + e) = acc_u;
    *reinterpret_cast<f4*>(out + 1 * NTOT + e) = acc_v;
    *reinterpret_cast<f4*>(out + 2 * NTOT + e) = acc_w;
    *reinterpret_cast<f4*>(out + 3 * NTOT + e) = acc_T;
    *reinterpret_cast<f4*>(out + 4 * NTOT + e) = acc_q;
    *reinterpret_cast<f4*>(out + 5 * NTOT + e) = acc_p;
    *reinterpret_cast<f4*>(out + 6 * NTOT + e) = acc_rho;
}

extern "C" void kernel_launch(void* const* d_in, const int* in_sizes, int n_in,
                              void* d_out, int out_size, void* d_ws, size_t ws_size,
                              hipStream_t stream) {
    const float* u     = (const float*)d_in[0];
    const float* v     = (const float*)d_in[1];
    const float* w     = (const float*)d_in[2];
    const float* T     = (const float*)d_in[3];
    const float* q     = (const float*)d_in[4];
    const float* p     = (const float*)d_in[5];
    const float* rho   = (const float*)d_in[6];
    const float* F_u   = (const float*)d_in[7];
    const float* F_v   = (const float*)d_in[8];
    const float* F_w   = (const float*)d_in[9];
    const float* Q     = (const float*)d_in[10];
    const float* S     = (const float*)d_in[11];
    const float* nu    = (const float*)d_in[12];
    const float* kappa = (const float*)d_in[13];
    float* out = (float*)d_out;

    const int threads = NTOT / 4;            // 1,572,864
    const int block = 256;
    const int grid = threads / block;        // 6144
    pe_tendencies_v2<<<grid, block, 0, stream>>>(u, v, w, T, q, p, rho,
                                                 F_u, F_v, F_w, Q, S,
                                                 nu, kappa, out);
}

// Round 3
// 179.022 us; speedup vs baseline: 1.4575x; 1.0520x over previous
//
#include <hip/hip_runtime.h>
#include <math.h>

typedef float f4 __attribute__((ext_vector_type(4)));

namespace {
constexpr int NZ = 48, NY = 256, NX = 512;
constexpr int SY = NX;           // y stride (elements)
constexpr int SZ = NX * NY;      // z stride (elements)
constexpr int NTOT = NZ * NY * NX;
constexpr float INV_DX = 1.0f / 100000.0f;
constexpr float INV_DY = 1.0f / 100000.0f;
constexpr float INV_DZ = 1.0f / 500.0f;
}

__device__ __forceinline__ f4 sp(float s) { return (f4){s, s, s, s}; }

__device__ __forceinline__ f4 ldv(const float* __restrict__ f, int e) {
    return *reinterpret_cast<const f4*>(f + e);
}

// ---- x-axis: per-element window [L | C | R], thread covers i = x0..x0+3 ----
__device__ __forceinline__ void grad2x(f4 L, f4 C, f4 R, int x0, float inv_h,
                                       f4& g, f4& gg) {
    const float h1 = inv_h, h2 = 0.5f * inv_h;
    float win[12] = {L[0], L[1], L[2], L[3], C[0], C[1], C[2], C[3],
                     R[0], R[1], R[2], R[3]};
#pragma unroll
    for (int j = 0; j < 4; ++j) {
        g[j]  = (win[5 + j] - win[3 + j]) * h2;
        gg[j] = ((win[6 + j] - win[4 + j]) * h2 - (win[4 + j] - win[2 + j]) * h2) * h2;
    }
    if (x0 == 0) {                       // i==0 and i==1 edge formulas
        g[0]  = (C[1] - C[0]) * h1;
        gg[0] = ((C[2] - C[0]) * h2 - g[0]) * h1;
        gg[1] = ((C[3] - C[1]) * h2 - (C[1] - C[0]) * h1) * h2;
    } else if (x0 == NX - 4) {           // i==n-2 and i==n-1
        gg[2] = ((C[3] - C[2]) * h1 - (C[2] - C[0]) * h2) * h2;
        g[3]  = (C[3] - C[2]) * h1;
        gg[3] = (g[3] - (C[3] - C[1]) * h2) * h1;
    }
}

__device__ __forceinline__ f4 grad1x(f4 L, f4 C, f4 R, int x0, float inv_h) {
    const float h1 = inv_h, h2 = 0.5f * inv_h;
    f4 g;
    g[0] = (C[1] - L[3]) * h2;
    g[1] = (C[2] - C[0]) * h2;
    g[2] = (C[3] - C[1]) * h2;
    g[3] = (R[0] - C[2]) * h2;
    if (x0 == 0)            g[0] = (C[1] - C[0]) * h1;
    else if (x0 == NX - 4)  g[3] = (C[3] - C[2]) * h1;
    return g;
}

// ---- y/z axes: whole-vector stencil, index i uniform across the f4 ----
__device__ __forceinline__ void grad2v(f4 m2, f4 m1, f4 c, f4 p1, f4 p2,
                                       int i, int n, float inv_h, f4& g, f4& gg) {
    const float h1 = inv_h, h2 = 0.5f * inv_h;
    if (i >= 2 && i <= n - 3) {
        g  = (p1 - m1) * sp(h2);
        gg = ((p2 - c) * sp(h2) - (c - m2) * sp(h2)) * sp(h2);
    } else if (i == 0) {
        g  = (p1 - c) * sp(h1);
        gg = ((p2 - c) * sp(h2) - g) * sp(h1);
    } else if (i == 1) {
        g  = (p1 - m1) * sp(h2);
        gg = ((p2 - c) * sp(h2) - (c - m1) * sp(h1)) * sp(h2);
    } else if (i == n - 2) {
        g  = (p1 - m1) * sp(h2);
        gg = ((p1 - c) * sp(h1) - (c - m2) * sp(h2)) * sp(h2);
    } else { // i == n-1
        g  = (c - m1) * sp(h1);
        gg = (g - (c - m2) * sp(h2)) * sp(h1);
    }
}

__device__ __forceinline__ f4 grad1v(f4 m1, f4 c, f4 p1, int i, int n, float inv_h) {
    if (i == 0)     return (p1 - c) * sp(inv_h);
    if (i == n - 1) return (c - m1) * sp(inv_h);
    return (p1 - m1) * sp(0.5f * inv_h);
}

struct Offs {
    int xm, xp;
    int m1y, m2y, p1y, p2y;
    int m1z, m2z, p1z, p2z;
    int x0, y, z;
};

__device__ __forceinline__ void field_grad2(const float* __restrict__ f, int e,
                                            const Offs& o, f4 C,
                                            f4& gx, f4& gy, f4& gz, f4& lap) {
    f4 L = ldv(f, e + o.xm);
    f4 R = ldv(f, e + o.xp);
    f4 gg;
    grad2x(L, C, R, o.x0, INV_DX, gx, gg);
    lap = gg;
    grad2v(ldv(f, e + o.m2y), ldv(f, e + o.m1y), C, ldv(f, e + o.p1y),
           ldv(f, e + o.p2y), o.y, NY, INV_DY, gy, gg);
    lap += gg;
    grad2v(ldv(f, e + o.m2z), ldv(f, e + o.m1z), C, ldv(f, e + o.p1z),
           ldv(f, e + o.p2z), o.z, NZ, INV_DZ, gz, gg);
    lap += gg;
}

__device__ __forceinline__ void field_grad1(const float* __restrict__ f, int e,
                                            const Offs& o, f4 C,
                                            f4& gx, f4& gy, f4& gz) {
    f4 L = ldv(f, e + o.xm);
    f4 R = ldv(f, e + o.xp);
    gx = grad1x(L, C, R, o.x0, INV_DX);
    gy = grad1v(ldv(f, e + o.m1y), C, ldv(f, e + o.p1y), o.y, NY, INV_DY);
    gz = grad1v(ldv(f, e + o.m1z), C, ldv(f, e + o.p1z), o.z, NZ, INV_DZ);
}

__global__ __launch_bounds__(256)
void pe_tendencies_v3(const float* __restrict__ u, const float* __restrict__ v,
                      const float* __restrict__ w, const float* __restrict__ T,
                      const float* __restrict__ q, const float* __restrict__ p,
                      const float* __restrict__ rho,
                      const float* __restrict__ F_u, const float* __restrict__ F_v,
                      const float* __restrict__ F_w, const float* __restrict__ Q,
                      const float* __restrict__ S,
                      const float* __restrict__ nu_p, const float* __restrict__ kappa_p,
                      float* __restrict__ out) {
    // XCD-aware remap: consecutive hw blocks round-robin over 8 XCDs; invert
    // so each XCD owns a 32-row y-band across all z, swept z-major. Keeps the
    // 5-plane z-window and all y-halos resident in that XCD's 4 MB L2.
    const int bid = blockIdx.x;
    const int xcd = bid & 7;
    const int j = bid >> 3;              // 0..767 within-XCD sequence
    const int z = j >> 4;                // 0..47, advances every 16 blocks
    const int yp = (xcd << 4) | (j & 15);      // y-pair 0..127 (band = 16 pairs)
    const int y = (yp << 1) | (threadIdx.x >> 7);   // row 0..255
    const int x0 = (threadIdx.x & 127) << 2;
    const int e = z * SZ + y * SY + x0;

    Offs o;
    o.x0 = x0; o.y = y; o.z = z;
    o.xm = (x0 > 0) ? -4 : 0;
    o.xp = (x0 < NX - 4) ? 4 : 0;
    o.m1y = (y > 0) ? -SY : 0;
    o.m2y = (y > 1) ? -2 * SY : o.m1y;
    o.p1y = (y < NY - 1) ? SY : 0;
    o.p2y = (y < NY - 2) ? 2 * SY : o.p1y;
    o.m1z = (z > 0) ? -SZ : 0;
    o.m2z = (z > 1) ? -2 * SZ : o.m1z;
    o.p1z = (z < NZ - 1) ? SZ : 0;
    o.p2z = (z < NZ - 2) ? 2 * SZ : o.p1z;

    const float nu = nu_p[0];
    const float kap = kappa_p[0];

    const f4 uc = ldv(u, e);
    const f4 vc = ldv(v, e);
    const f4 wc = ldv(w, e);

    f4 gx, gy, gz, lap;

    // u
    field_grad2(u, e, o, uc, gx, gy, gz, lap);
    f4 du_dx = gx;
    f4 acc_u = sp(nu) * lap - (uc * gx + vc * gy + wc * gz);
    // v
    field_grad2(v, e, o, vc, gx, gy, gz, lap);
    f4 dv_dy = gy;
    f4 acc_v = sp(nu) * lap - (uc * gx + vc * gy + wc * gz);
    // w
    field_grad2(w, e, o, wc, gx, gy, gz, lap);
    f4 dw_dz = gz;
    f4 acc_w = sp(nu) * lap - (uc * gx + vc * gy + wc * gz);

    f4 div = du_dx + dv_dy + dw_dz;

    // T
    const f4 Tc = ldv(T, e);
    field_grad2(T, e, o, Tc, gx, gy, gz, lap);
    f4 acc_T = sp(kap) * lap - (uc * gx + vc * gy + wc * gz);

    // rho (grad1)
    const f4 rhoc = ldv(rho, e);
    field_grad1(rho, e, o, rhoc, gx, gy, gz);
    f4 acc_rho = -rhoc * div - uc * gx - vc * gy - wc * gz;

    // p (grad1)
    const f4 pc = ldv(p, e);
    field_grad1(p, e, o, pc, gx, gy, gz);
    const f4 inv_rs = sp(1.0f) / (rhoc + sp(1e-10f));
    acc_u -= gx * inv_rs;
    acc_v -= gy * inv_rs;
    acc_w -= gz * inv_rs;
    acc_T += sp(287.0f / 1004.0f) * Tc * wc * gz / (pc + sp(1e-10f));

    // q (grad1)
    const f4 qc = ldv(q, e);
    field_grad1(q, e, o, qc, gx, gy, gz);
    f4 acc_q = -(uc * gx + vc * gy + wc * gz);

    // Coriolis
    const double lat = -M_PI * 0.5 + (M_PI / 255.0) * (double)y;
    const float fc = 2.0f * 7.2921e-5f * (float)sin(lat);
    acc_u += sp(fc) * vc;
    acc_v -= sp(fc) * uc;

    // forcings / sources
    acc_u += ldv(F_u, e);
    acc_v += ldv(F_v, e);
    acc_w += ldv(F_w, e) - sp(9.80665f);
    acc_T += ldv(Q, e) * sp(1.0f / 1004.0f);
    acc_q += ldv(S, e);

    const f4 acc_p = sp(287.0f) * (rhoc * acc_T + Tc * acc_rho);

    *reinterpret_cast<f4*>(out + 0 * NTOT + e) = acc_u;
    *reinterpret_cast<f4*>(out + 1 * NTOT + e) = acc_v;
    *reinterpret_cast<f4*>(out + 2 * NTOT + e) = acc_w;
    *reinterpret_cast<f4*>(out + 3 * NTOT + e) = acc_T;
    *reinterpret_cast<f4*>(out + 4 * NTOT + e) = acc_q;
    *reinterpret_cast<f4*>(out + 5 * NTOT + e) = acc_p;
    *reinterpret_cast<f4*>(out + 6 * NTOT + e) = acc_rho;
}

extern "C" void kernel_launch(void* const* d_in, const int* in_sizes, int n_in,
                              void* d_out, int out_size, void* d_ws, size_t ws_size,
                              hipStream_t stream) {
    const float* u     = (const float*)d_in[0];
    const float* v     = (const float*)d_in[1];
    const float* w     = (const float*)d_in[2];
    const float* T     = (const float*)d_in[3];
    const float* q     = (const float*)d_in[4];
    const float* p     = (const float*)d_in[5];
    const float* rho   = (const float*)d_in[6];
    const float* F_u   = (const float*)d_in[7];
    const float* F_v   = (const float*)d_in[8];
    const float* F_w   = (const float*)d_in[9];
    const float* Q     = (const float*)d_in[10];
    const float* S     = (const float*)d_in[11];
    const float* nu    = (const float*)d_in[12];
    const float* kappa = (const float*)d_in[13];
    float* out = (float*)d_out;

    const int threads = NTOT / 4;            // 1,572,864
    const int block = 256;
    const int grid = threads / block;        // 6144
    pe_tendencies_v3<<<grid, block, 0, stream>>>(u, v, w, T, q, p, rho,
                                                 F_u, F_v, F_w, Q, S,
                                                 nu, kappa, out);
}